// Round 1
// baseline (891.068 us; speedup 1.0000x reference)
//
#include <hip/hip_runtime.h>
#include <hip/hip_bf16.h>
#include <cmath>

#define D_MODEL 512
#define D_INNER 1024
#define NHEAD 16
#define HDIM 64
#define NSTATE 16
#define DPROJ 2096   // 2*D_INNER + 2*NS + NH
#define NB 8
#define NT 64
#define NW 16
#define MROWS 8192   // NB*NT*NW

// ---------------- block-wide sum reduction (256 threads = 4 waves) ----------
__device__ __forceinline__ float block_sum(float v, float* sbuf) {
#pragma unroll
  for (int o = 32; o > 0; o >>= 1) v += __shfl_down(v, o, 64);
  int lane = threadIdx.x & 63, wid = threadIdx.x >> 6;
  int nw = blockDim.x >> 6;
  if (lane == 0) sbuf[wid] = v;
  __syncthreads();
  if (threadIdx.x == 0) {
    float t = 0.f;
    for (int i = 0; i < nw; i++) t += sbuf[i];
    sbuf[0] = t;
  }
  __syncthreads();
  return sbuf[0];
}

// ---------------- LayerNorm over D_MODEL=512, one block per row -------------
__global__ __launch_bounds__(256) void ln512_kernel(
    const float* __restrict__ x, const float* __restrict__ w,
    const float* __restrict__ b, float* __restrict__ out) {
  __shared__ float s1[8], s2[8];
  int row = blockIdx.x;
  const float* xr = x + (size_t)row * D_MODEL;
  float* outr = out + (size_t)row * D_MODEL;
  int c0 = threadIdx.x, c1 = threadIdx.x + 256;
  float v0 = xr[c0], v1 = xr[c1];
  float s  = block_sum(v0 + v1, s1);
  float ss = block_sum(v0 * v0 + v1 * v1, s2);
  float mean = s * (1.f / 512.f);
  float var  = ss * (1.f / 512.f) - mean * mean;
  float inv  = rsqrtf(var + 1e-5f);
  outr[c0] = (v0 - mean) * inv * w[c0] + b[c0];
  outr[c1] = (v1 - mean) * inv * w[c1] + b[c1];
}

// ---------------- fp32 tiled GEMM: C = A[M,K] @ B[K,N] (+bias)(+resid) ------
// 64x64 tile, BK=16, 256 threads, 4x4 micro-tile. A-tile stored transposed.
__global__ __launch_bounds__(256) void gemm64_kernel(
    const float* __restrict__ A, const float* __restrict__ B,
    const float* __restrict__ bias, const float* __restrict__ resid,
    float* __restrict__ C, int M, int N, int K) {
  const int BK = 16;
  __shared__ __align__(16) float As[16][64];  // [k][m]
  __shared__ __align__(16) float Bs[16][64];  // [k][n]
  int tx = threadIdx.x & 15, ty = threadIdx.x >> 4;
  int row0 = blockIdx.y * 64, col0 = blockIdx.x * 64;
  float acc[4][4] = {{0.f}};
  int ar = threadIdx.x >> 2, akc = (threadIdx.x & 3) * 4;
  int bkr = threadIdx.x >> 4, bc = (threadIdx.x & 15) * 4;

  for (int k0 = 0; k0 < K; k0 += BK) {
    float4 av = *(const float4*)&A[(size_t)(row0 + ar) * K + k0 + akc];
    As[akc + 0][ar] = av.x;
    As[akc + 1][ar] = av.y;
    As[akc + 2][ar] = av.z;
    As[akc + 3][ar] = av.w;
    int bcol = col0 + bc;
    float4 bv;
    if (bcol + 3 < N) {
      bv = *(const float4*)&B[(size_t)(k0 + bkr) * N + bcol];
    } else {
      bv.x = (bcol + 0 < N) ? B[(size_t)(k0 + bkr) * N + bcol + 0] : 0.f;
      bv.y = (bcol + 1 < N) ? B[(size_t)(k0 + bkr) * N + bcol + 1] : 0.f;
      bv.z = (bcol + 2 < N) ? B[(size_t)(k0 + bkr) * N + bcol + 2] : 0.f;
      bv.w = 0.f;
    }
    *(float4*)&Bs[bkr][bc] = bv;
    __syncthreads();
#pragma unroll
    for (int kk = 0; kk < BK; kk++) {
      float4 aq = *(const float4*)&As[kk][ty * 4];
      float4 bq = *(const float4*)&Bs[kk][tx * 4];
      float a_[4] = {aq.x, aq.y, aq.z, aq.w};
      float b_[4] = {bq.x, bq.y, bq.z, bq.w};
#pragma unroll
      for (int i = 0; i < 4; i++)
#pragma unroll
        for (int j = 0; j < 4; j++) acc[i][j] += a_[i] * b_[j];
    }
    __syncthreads();
  }
#pragma unroll
  for (int i = 0; i < 4; i++) {
    int row = row0 + ty * 4 + i;
#pragma unroll
    for (int j = 0; j < 4; j++) {
      int col = col0 + tx * 4 + j;
      if (col < N) {
        float v = acc[i][j];
        if (bias) v += bias[col];
        if (resid) v += resid[(size_t)row * N + col];
        C[(size_t)row * N + col] = v;
      }
    }
  }
}

// ---------------- tree scan: one block per (b, h, p-chunk of 16) ------------
// State slice [W=16][Pchunk=16][N=16] lives in LDS (padded to 17).
__global__ __launch_bounds__(256) void tree_scan_kernel(
    const float* __restrict__ proj, const int* __restrict__ parent,
    const float* __restrict__ A_log, const float* __restrict__ dt_bias,
    const float* __restrict__ Dp, float* __restrict__ y) {
  int ps = blockIdx.x & 3;
  int h  = (blockIdx.x >> 2) & 15;
  int b  = blockIdx.x >> 6;
  int w  = threadIdx.x >> 4;
  int pl = threadIdx.x & 15;
  int p  = (ps << 4) + pl;

  __shared__ float hbuf[16][16][17];  // [w][pl][n], pad 17 vs bank stride
  __shared__ float bcs[16][2][16];    // staged B,C vectors per w

#pragma unroll
  for (int n = 0; n < 16; n++) hbuf[w][pl][n] = 0.f;

  float Ah  = -expf(A_log[h]);
  float dtb = dt_bias[h];
  float Dh  = Dp[h];
  __syncthreads();

  for (int t = 0; t < NT; t++) {
    size_t rowidx = ((size_t)b * NT + t) * NW + w;
    const float* pr = proj + rowidx * DPROJ;
    int par = parent[rowidx];
    float dtr = pr[2080 + h] + dtb;
    float dt = (dtr > 20.f) ? dtr : log1pf(expf(dtr));  // softplus
    float dA = expf(dt * Ah);
    float xv = pr[1024 + (h << 6) + p];
    float hp[16];
#pragma unroll
    for (int n = 0; n < 16; n++) hp[n] = hbuf[par][pl][n];
    bcs[w][0][pl] = pr[2048 + pl];
    bcs[w][1][pl] = pr[2064 + pl];
    __syncthreads();  // hp reads done; bcs visible
    float dtx = dt * xv;
    float yv = 0.f;
#pragma unroll
    for (int n = 0; n < 16; n++) {
      float hn = dA * hp[n] + dtx * bcs[w][0][n];
      hbuf[w][pl][n] = hn;
      yv += hn * bcs[w][1][n];
    }
    y[rowidx * D_INNER + (h << 6) + p] = yv + Dh * xv;  // fused D*x skip
    __syncthreads();  // h writes visible before next gather
  }
}

// ---------------- gated RMSNorm: yg = rms(y * silu(z)) * norm_w -------------
__global__ __launch_bounds__(256) void gate_rms_kernel(
    const float* __restrict__ yin, const float* __restrict__ proj,
    const float* __restrict__ norm_w, float* __restrict__ out) {
  __shared__ float sbuf[8];
  int row = blockIdx.x;
  const float* yr = yin + (size_t)row * D_INNER;
  const float* zr = proj + (size_t)row * DPROJ;  // z = proj[:, 0:1024]
  int c = threadIdx.x * 4;
  float4 y4 = *(const float4*)&yr[c];
  float4 z4 = *(const float4*)&zr[c];
  const float* yp = (const float*)&y4;
  const float* zp = (const float*)&z4;
  float gv[4];
  float ss = 0.f;
#pragma unroll
  for (int j = 0; j < 4; j++) {
    float z = zp[j];
    float t = yp[j] * (z / (1.f + expf(-z)));
    gv[j] = t;
    ss += t * t;
  }
  ss = block_sum(ss, sbuf);
  float scale = rsqrtf(ss * (1.f / 1024.f) + 1e-5f);
  float4 o;
  float* op = (float*)&o;
#pragma unroll
  for (int j = 0; j < 4; j++) op[j] = gv[j] * scale * norm_w[c + j];
  *(float4*)&out[(size_t)row * D_INNER + c] = o;
}

// ---------------- FF gate: fg = f1 * silu(g) --------------------------------
__global__ __launch_bounds__(256) void ffgate_kernel(
    const float* __restrict__ f, float* __restrict__ out) {
  size_t i4 = (size_t)blockIdx.x * blockDim.x + threadIdx.x;  // 2M float4s
  int row = (int)(i4 >> 8);
  int c = ((int)i4 & 255) * 4;
  const float* fr = f + (size_t)row * 2048;
  float4 a = *(const float4*)&fr[c];
  float4 g = *(const float4*)&fr[1024 + c];
  const float* ap = (const float*)&a;
  const float* gp = (const float*)&g;
  float4 o;
  float* op = (float*)&o;
#pragma unroll
  for (int j = 0; j < 4; j++) {
    float z = gp[j];
    op[j] = ap[j] * (z / (1.f + expf(-z)));
  }
  *(float4*)&out[(size_t)row * 1024 + c] = o;
}

extern "C" void kernel_launch(void* const* d_in, const int* in_sizes, int n_in,
                              void* d_out, int out_size, void* d_ws, size_t ws_size,
                              hipStream_t stream) {
  const float* x       = (const float*)d_in[0];
  const int*   parent  = (const int*)d_in[1];
  const float* ln1_w   = (const float*)d_in[2];
  const float* ln1_b   = (const float*)d_in[3];
  const float* in_w    = (const float*)d_in[4];
  const float* in_b    = (const float*)d_in[5];
  const float* A_log   = (const float*)d_in[6];
  const float* dt_bias = (const float*)d_in[7];
  const float* Dp      = (const float*)d_in[8];
  const float* norm_w  = (const float*)d_in[9];
  const float* out_w   = (const float*)d_in[10];
  const float* out_b   = (const float*)d_in[11];
  const float* ln2_w   = (const float*)d_in[12];
  const float* ln2_b   = (const float*)d_in[13];
  const float* ff1_w   = (const float*)d_in[14];
  const float* ff1_b   = (const float*)d_in[15];
  const float* ff2_w   = (const float*)d_in[16];
  const float* ff2_b   = (const float*)d_in[17];
  float* outp = (float*)d_out;

  float* xn   = (float*)d_ws;                      // [8192,512]
  float* proj = xn + (size_t)MROWS * D_MODEL;      // [8192,2096] (reused for f)
  float* yb   = proj + (size_t)MROWS * DPROJ;      // [8192,1024] (reused for fg)
  float* xmid = outp;                              // d_out doubles as xmid

  dim3 blk(256);
  // 1) LN1
  ln512_kernel<<<MROWS, blk, 0, stream>>>(x, ln1_w, ln1_b, xn);
  // 2) in-proj GEMM -> proj
  {
    dim3 g((DPROJ + 63) / 64, MROWS / 64);
    gemm64_kernel<<<g, blk, 0, stream>>>(xn, in_w, in_b, nullptr, proj,
                                         MROWS, DPROJ, D_MODEL);
  }
  // 3) tree scan (+ D*x skip fused) -> yb
  tree_scan_kernel<<<NB * NHEAD * 4, blk, 0, stream>>>(proj, parent, A_log,
                                                       dt_bias, Dp, yb);
  // 4) gated RMSNorm (in-place on yb)
  gate_rms_kernel<<<MROWS, blk, 0, stream>>>(yb, proj, norm_w, yb);
  // 5) out-proj GEMM + residual(x) -> xmid (= d_out)
  {
    dim3 g(D_MODEL / 64, MROWS / 64);
    gemm64_kernel<<<g, blk, 0, stream>>>(yb, out_w, out_b, x, xmid,
                                         MROWS, D_MODEL, D_INNER);
  }
  // 6) LN2 -> xn (reuse)
  ln512_kernel<<<MROWS, blk, 0, stream>>>(xmid, ln2_w, ln2_b, xn);
  // 7) FF1 GEMM -> proj (reuse, needs 8192*2048 <= 8192*2096)
  {
    dim3 g(2048 / 64, MROWS / 64);
    gemm64_kernel<<<g, blk, 0, stream>>>(xn, ff1_w, ff1_b, nullptr, proj,
                                         MROWS, 2048, D_MODEL);
  }
  // 8) FF gate -> yb (reuse)
  ffgate_kernel<<<8192, blk, 0, stream>>>(proj, yb);
  // 9) FF2 GEMM + residual(xmid) -> d_out (in-place safe: 1 elem per thread)
  {
    dim3 g(D_MODEL / 64, MROWS / 64);
    gemm64_kernel<<<g, blk, 0, stream>>>(yb, ff2_w, ff2_b, xmid, outp,
                                         MROWS, D_MODEL, D_INNER);
  }
}

// Round 2
// 298.544 us; speedup vs baseline: 2.9847x; 2.9847x over previous
//
#include <hip/hip_runtime.h>
#include <hip/hip_bf16.h>
#include <cmath>

#define D_MODEL 512
#define D_INNER 1024
#define NHEAD 16
#define HDIM 64
#define NSTATE 16
#define NB 8
#define NT 64
#define NW 16
#define MROWS 8192      // NB*NT*NW
#define PROJ_LD 2176    // padded 2096 -> 17*128
#define NPROJ 2096

typedef __attribute__((ext_vector_type(8))) short short8;
typedef __attribute__((ext_vector_type(4))) float f32x4;
typedef __hip_bfloat16 bf16;

// ---------------- block-wide sum reduction (256 threads = 4 waves) ----------
__device__ __forceinline__ float block_sum(float v, float* sbuf) {
#pragma unroll
  for (int o = 32; o > 0; o >>= 1) v += __shfl_down(v, o, 64);
  int lane = threadIdx.x & 63, wid = threadIdx.x >> 6;
  if (lane == 0) sbuf[wid] = v;
  __syncthreads();
  if (threadIdx.x == 0) {
    float t = 0.f;
    for (int i = 0; i < 4; i++) t += sbuf[i];
    sbuf[0] = t;
  }
  __syncthreads();
  return sbuf[0];
}

// ---------------- LayerNorm over 512, bf16 out ------------------------------
__global__ __launch_bounds__(256) void ln512_bf16_kernel(
    const float* __restrict__ x, const float* __restrict__ w,
    const float* __restrict__ b, bf16* __restrict__ out) {
  __shared__ float s1[8], s2[8];
  int row = blockIdx.x;
  const float* xr = x + (size_t)row * D_MODEL;
  bf16* outr = out + (size_t)row * D_MODEL;
  int c0 = threadIdx.x, c1 = threadIdx.x + 256;
  float v0 = xr[c0], v1 = xr[c1];
  float s  = block_sum(v0 + v1, s1);
  float ss = block_sum(v0 * v0 + v1 * v1, s2);
  float mean = s * (1.f / 512.f);
  float var  = ss * (1.f / 512.f) - mean * mean;
  float inv  = rsqrtf(var + 1e-5f);
  outr[c0] = __float2bfloat16((v0 - mean) * inv * w[c0] + b[c0]);
  outr[c1] = __float2bfloat16((v1 - mean) * inv * w[c1] + b[c1]);
}

// ---------------- weight convert + transpose: fp32 [K][N] -> bf16 [Npad][K] -
__global__ __launch_bounds__(256) void wconv_t_kernel(
    const float* __restrict__ w, bf16* __restrict__ wt,
    int K, int N, int Npad) {
  __shared__ float tile[32][33];
  int n0 = blockIdx.x * 32, k0 = blockIdx.y * 32;
  int tx = threadIdx.x & 31, ty = threadIdx.x >> 5;  // 32 x 8
#pragma unroll
  for (int i = 0; i < 4; i++) {
    int k = k0 + ty + i * 8, n = n0 + tx;
    tile[ty + i * 8][tx] = (k < K && n < N) ? w[(size_t)k * N + n] : 0.f;
  }
  __syncthreads();
#pragma unroll
  for (int i = 0; i < 4; i++) {
    int n = n0 + ty + i * 8, k = k0 + tx;
    if (n < Npad && k < K) wt[(size_t)n * K + k] = __float2bfloat16(tile[tx][ty + i * 8]);
  }
}

// ---------------- bf16 MFMA GEMM: C[M,N] = A[M,K] @ Bt[N,K]^T ---------------
// m97 structure: BK=32, global_load_lds(16B), linear LDS, 2 barriers/K-step.
template<int BM, int BN, int WN, int MR, int NR>
__global__ __launch_bounds__(256) void mfma_gemm_kernel(
    const bf16* __restrict__ A, const bf16* __restrict__ Bt,
    const float* __restrict__ bias, int nbias,
    const float* __restrict__ resid,
    float* __restrict__ C, int ldc, int K) {
  constexpr int ROWS = BM + BN;            // LDS rows, 64 B each
  constexpr int ISS  = ROWS / 64;          // global_load_lds issues per wave
  __shared__ __align__(16) bf16 sAB[ROWS][32];  // A rows then B(t) rows

  int wid = threadIdx.x >> 6, lane = threadIdx.x & 63;
  int row0 = blockIdx.y * BM, col0 = blockIdx.x * BN;
  int wr = (wid / WN) * (MR * 16);
  int wc = (wid % WN) * (NR * 16);

  f32x4 acc[MR][NR];
#pragma unroll
  for (int m = 0; m < MR; m++)
#pragma unroll
    for (int n = 0; n < NR; n++) acc[m][n] = (f32x4){0.f, 0.f, 0.f, 0.f};

  int lr = lane >> 2;            // row within 16-row issue group
  int lc = (lane & 3) * 8;       // bf16 offset within 64B row

  for (int k0 = 0; k0 < K; k0 += 32) {
#pragma unroll
    for (int i = 0; i < ISS; i++) {
      int rb = (wid * ISS + i) * 16;
      int r = rb + lr;
      const bf16* src = (r < BM)
          ? A  + (size_t)(row0 + r) * K + k0 + lc
          : Bt + (size_t)(col0 + (r - BM)) * K + k0 + lc;
      __builtin_amdgcn_global_load_lds(
          (const __attribute__((address_space(1))) void*)src,
          (__attribute__((address_space(3))) void*)&sAB[rb][0], 16, 0, 0);
    }
    asm volatile("s_waitcnt vmcnt(0)" ::: "memory");
    __syncthreads();

    short8 a[MR], b[NR];
    int kk = (lane >> 4) * 8;
#pragma unroll
    for (int m = 0; m < MR; m++)
      a[m] = *(const short8*)&sAB[wr + m * 16 + (lane & 15)][kk];
#pragma unroll
    for (int n = 0; n < NR; n++)
      b[n] = *(const short8*)&sAB[BM + wc + n * 16 + (lane & 15)][kk];
#pragma unroll
    for (int m = 0; m < MR; m++)
#pragma unroll
      for (int n = 0; n < NR; n++)
        acc[m][n] = __builtin_amdgcn_mfma_f32_16x16x32_bf16(a[m], b[n], acc[m][n], 0, 0, 0);
    __syncthreads();
  }

  int crow = row0 + wr + (lane >> 4) * 4;
  int ccol = col0 + wc + (lane & 15);
#pragma unroll
  for (int m = 0; m < MR; m++) {
#pragma unroll
    for (int n = 0; n < NR; n++) {
      int colg = ccol + n * 16;
      float bv = bias ? ((colg < nbias) ? bias[colg] : 0.f) : 0.f;
#pragma unroll
      for (int j = 0; j < 4; j++) {
        int rowg = crow + m * 16 + j;
        float v = acc[m][n][j] + bv;
        if (resid) v += resid[(size_t)rowg * ldc + colg];
        C[(size_t)rowg * ldc + colg] = v;
      }
    }
  }
}

// ---------------- tree scan: one block per (b, h, p-chunk of 16) ------------
__global__ __launch_bounds__(256) void tree_scan_kernel(
    const float* __restrict__ proj, const int* __restrict__ parent,
    const float* __restrict__ A_log, const float* __restrict__ dt_bias,
    const float* __restrict__ Dp, float* __restrict__ y) {
  int ps = blockIdx.x & 3;
  int h  = (blockIdx.x >> 2) & 15;
  int b  = blockIdx.x >> 6;
  int w  = threadIdx.x >> 4;
  int pl = threadIdx.x & 15;
  int p  = (ps << 4) + pl;

  __shared__ float hbuf[16][16][17];
  __shared__ float bcs[16][2][16];

#pragma unroll
  for (int n = 0; n < 16; n++) hbuf[w][pl][n] = 0.f;

  float Ah  = -expf(A_log[h]);
  float dtb = dt_bias[h];
  float Dh  = Dp[h];
  __syncthreads();

  for (int t = 0; t < NT; t++) {
    size_t rowidx = ((size_t)b * NT + t) * NW + w;
    const float* pr = proj + rowidx * PROJ_LD;
    int par = parent[rowidx];
    float dtr = pr[2080 + h] + dtb;
    float dt = (dtr > 20.f) ? dtr : log1pf(expf(dtr));
    float dA = expf(dt * Ah);
    float xv = pr[1024 + (h << 6) + p];
    float hp[16];
#pragma unroll
    for (int n = 0; n < 16; n++) hp[n] = hbuf[par][pl][n];
    bcs[w][0][pl] = pr[2048 + pl];
    bcs[w][1][pl] = pr[2064 + pl];
    __syncthreads();
    float dtx = dt * xv;
    float yv = 0.f;
#pragma unroll
    for (int n = 0; n < 16; n++) {
      float hn = dA * hp[n] + dtx * bcs[w][0][n];
      hbuf[w][pl][n] = hn;
      yv += hn * bcs[w][1][n];
    }
    y[rowidx * D_INNER + (h << 6) + p] = yv + Dh * xv;
    __syncthreads();
  }
}

// ---------------- gated RMSNorm -> bf16 -------------------------------------
__global__ __launch_bounds__(256) void gate_rms_kernel(
    const float* __restrict__ yin, const float* __restrict__ proj,
    const float* __restrict__ norm_w, bf16* __restrict__ out) {
  __shared__ float sbuf[8];
  int row = blockIdx.x;
  const float* yr = yin + (size_t)row * D_INNER;
  const float* zr = proj + (size_t)row * PROJ_LD;  // z = cols [0,1024)
  int c = threadIdx.x * 4;
  float4 y4 = *(const float4*)&yr[c];
  float4 z4 = *(const float4*)&zr[c];
  const float* yp = (const float*)&y4;
  const float* zp = (const float*)&z4;
  float gv[4];
  float ss = 0.f;
#pragma unroll
  for (int j = 0; j < 4; j++) {
    float z = zp[j];
    float t = yp[j] * (z / (1.f + expf(-z)));
    gv[j] = t;
    ss += t * t;
  }
  ss = block_sum(ss, sbuf);
  float scale = rsqrtf(ss * (1.f / 1024.f) + 1e-5f);
  bf16 o4[4];
#pragma unroll
  for (int j = 0; j < 4; j++) o4[j] = __float2bfloat16(gv[j] * scale * norm_w[c + j]);
  *(uint2*)&out[(size_t)row * D_INNER + c] = *(uint2*)o4;
}

// ---------------- FF gate -> bf16 -------------------------------------------
__global__ __launch_bounds__(256) void ffgate_kernel(
    const float* __restrict__ f, bf16* __restrict__ out) {
  size_t i4 = (size_t)blockIdx.x * blockDim.x + threadIdx.x;
  int row = (int)(i4 >> 8);
  int c = ((int)i4 & 255) * 4;
  const float* fr = f + (size_t)row * 2048;
  float4 a = *(const float4*)&fr[c];
  float4 g = *(const float4*)&fr[1024 + c];
  const float* ap = (const float*)&a;
  const float* gp = (const float*)&g;
  bf16 o4[4];
#pragma unroll
  for (int j = 0; j < 4; j++) {
    float z = gp[j];
    o4[j] = __float2bfloat16(ap[j] * (z / (1.f + expf(-z))));
  }
  *(uint2*)&out[(size_t)row * 1024 + c] = *(uint2*)o4;
}

extern "C" void kernel_launch(void* const* d_in, const int* in_sizes, int n_in,
                              void* d_out, int out_size, void* d_ws, size_t ws_size,
                              hipStream_t stream) {
  const float* x       = (const float*)d_in[0];
  const int*   parent  = (const int*)d_in[1];
  const float* ln1_w   = (const float*)d_in[2];
  const float* ln1_b   = (const float*)d_in[3];
  const float* in_w    = (const float*)d_in[4];
  const float* in_b    = (const float*)d_in[5];
  const float* A_log   = (const float*)d_in[6];
  const float* dt_bias = (const float*)d_in[7];
  const float* Dp      = (const float*)d_in[8];
  const float* norm_w  = (const float*)d_in[9];
  const float* out_w   = (const float*)d_in[10];
  const float* out_b   = (const float*)d_in[11];
  const float* ln2_w   = (const float*)d_in[12];
  const float* ln2_b   = (const float*)d_in[13];
  const float* ff1_w   = (const float*)d_in[14];
  const float* ff1_b   = (const float*)d_in[15];
  const float* ff2_w   = (const float*)d_in[16];
  const float* ff2_b   = (const float*)d_in[17];
  float* outp = (float*)d_out;

  char* wp = (char*)d_ws;
  bf16* xnb    = (bf16*)wp;  wp += (size_t)MROWS * D_MODEL * 2;
  bf16* in_wt  = (bf16*)wp;  wp += (size_t)PROJ_LD * D_MODEL * 2;
  bf16* out_wt = (bf16*)wp;  wp += (size_t)D_MODEL * D_INNER * 2;
  bf16* ff1_wt = (bf16*)wp;  wp += (size_t)2048 * D_MODEL * 2;
  bf16* ff2_wt = (bf16*)wp;  wp += (size_t)D_MODEL * D_INNER * 2;
  float* proj  = (float*)wp; wp += (size_t)MROWS * PROJ_LD * 4;  // reused for f
  float* yb    = (float*)wp; wp += (size_t)MROWS * D_INNER * 4;
  bf16* ygb    = (bf16*)wp;  wp += (size_t)MROWS * D_INNER * 2;
  float* xmid  = outp;  // d_out doubles as xmid

  dim3 blk(256);
  // weight converts (transpose to [N][K] bf16)
  wconv_t_kernel<<<dim3(PROJ_LD / 32, D_MODEL / 32), blk, 0, stream>>>(
      in_w, in_wt, D_MODEL, NPROJ, PROJ_LD);
  wconv_t_kernel<<<dim3(D_MODEL / 32, D_INNER / 32), blk, 0, stream>>>(
      out_w, out_wt, D_INNER, D_MODEL, D_MODEL);
  wconv_t_kernel<<<dim3(2048 / 32, D_MODEL / 32), blk, 0, stream>>>(
      ff1_w, ff1_wt, D_MODEL, 2048, 2048);
  wconv_t_kernel<<<dim3(D_MODEL / 32, D_INNER / 32), blk, 0, stream>>>(
      ff2_w, ff2_wt, D_INNER, D_MODEL, D_MODEL);

  // 1) LN1 -> bf16
  ln512_bf16_kernel<<<MROWS, blk, 0, stream>>>(x, ln1_w, ln1_b, xnb);
  // 2) in-proj GEMM -> proj (fp32, padded ld)
  mfma_gemm_kernel<128, 128, 2, 4, 4><<<dim3(PROJ_LD / 128, MROWS / 128), blk, 0, stream>>>(
      xnb, in_wt, in_b, NPROJ, nullptr, proj, PROJ_LD, D_MODEL);
  // 3) tree scan -> yb
  tree_scan_kernel<<<NB * NHEAD * 4, blk, 0, stream>>>(proj, parent, A_log,
                                                       dt_bias, Dp, yb);
  // 4) gated RMSNorm -> ygb (bf16)
  gate_rms_kernel<<<MROWS, blk, 0, stream>>>(yb, proj, norm_w, ygb);
  // 5) out-proj GEMM + resid(x) -> xmid
  mfma_gemm_kernel<64, 128, 4, 4, 2><<<dim3(D_MODEL / 128, MROWS / 64), blk, 0, stream>>>(
      ygb, out_wt, out_b, D_MODEL, x, xmid, D_MODEL, D_INNER);
  // 6) LN2 -> xnb (reuse)
  ln512_bf16_kernel<<<MROWS, blk, 0, stream>>>(xmid, ln2_w, ln2_b, xnb);
  // 7) FF1 GEMM -> f (reuse proj buffer, ld 2048)
  mfma_gemm_kernel<128, 128, 2, 4, 4><<<dim3(2048 / 128, MROWS / 128), blk, 0, stream>>>(
      xnb, ff1_wt, ff1_b, 2048, nullptr, proj, 2048, D_MODEL);
  // 8) FF gate -> ygb (reuse)
  ffgate_kernel<<<MROWS, blk, 0, stream>>>(proj, ygb);
  // 9) FF2 GEMM + resid(xmid) -> d_out
  mfma_gemm_kernel<64, 128, 4, 4, 2><<<dim3(D_MODEL / 128, MROWS / 64), blk, 0, stream>>>(
      ygb, ff2_wt, ff2_b, D_MODEL, xmid, outp, D_MODEL, D_INNER);
}

// Round 3
// 266.095 us; speedup vs baseline: 3.3487x; 1.1219x over previous
//
#include <hip/hip_runtime.h>
#include <hip/hip_bf16.h>
#include <cmath>

#define D_MODEL 512
#define D_INNER 1024
#define NHEAD 16
#define HDIM 64
#define NSTATE 16
#define NB 8
#define NT 64
#define NW 16
#define MROWS 8192      // NB*NT*NW
#define PROJ_LD 2176    // padded 2096 -> 17*128
#define NPROJ 2096

typedef __attribute__((ext_vector_type(8))) short short8;
typedef __attribute__((ext_vector_type(4))) float f32x4;
typedef __hip_bfloat16 bf16;

// ---------------- block-wide sum reduction (256 threads = 4 waves) ----------
__device__ __forceinline__ float block_sum(float v, float* sbuf) {
#pragma unroll
  for (int o = 32; o > 0; o >>= 1) v += __shfl_down(v, o, 64);
  int lane = threadIdx.x & 63, wid = threadIdx.x >> 6;
  if (lane == 0) sbuf[wid] = v;
  __syncthreads();
  if (threadIdx.x == 0) {
    float t = 0.f;
    for (int i = 0; i < 4; i++) t += sbuf[i];
    sbuf[0] = t;
  }
  __syncthreads();
  return sbuf[0];
}

// ---------------- LayerNorm over 512, bf16 out ------------------------------
__global__ __launch_bounds__(256) void ln512_bf16_kernel(
    const float* __restrict__ x, const float* __restrict__ w,
    const float* __restrict__ b, bf16* __restrict__ out) {
  __shared__ float s1[8], s2[8];
  int row = blockIdx.x;
  const float* xr = x + (size_t)row * D_MODEL;
  bf16* outr = out + (size_t)row * D_MODEL;
  int c0 = threadIdx.x, c1 = threadIdx.x + 256;
  float v0 = xr[c0], v1 = xr[c1];
  float s  = block_sum(v0 + v1, s1);
  float ss = block_sum(v0 * v0 + v1 * v1, s2);
  float mean = s * (1.f / 512.f);
  float var  = ss * (1.f / 512.f) - mean * mean;
  float inv  = rsqrtf(var + 1e-5f);
  outr[c0] = __float2bfloat16((v0 - mean) * inv * w[c0] + b[c0]);
  outr[c1] = __float2bfloat16((v1 - mean) * inv * w[c1] + b[c1]);
}

// ---------------- weight convert + transpose: fp32 [K][N] -> bf16 [Npad][K] -
__global__ __launch_bounds__(256) void wconv_t_kernel(
    const float* __restrict__ w, bf16* __restrict__ wt,
    int K, int N, int Npad) {
  __shared__ float tile[32][33];
  int n0 = blockIdx.x * 32, k0 = blockIdx.y * 32;
  int tx = threadIdx.x & 31, ty = threadIdx.x >> 5;  // 32 x 8
#pragma unroll
  for (int i = 0; i < 4; i++) {
    int k = k0 + ty + i * 8, n = n0 + tx;
    tile[ty + i * 8][tx] = (k < K && n < N) ? w[(size_t)k * N + n] : 0.f;
  }
  __syncthreads();
#pragma unroll
  for (int i = 0; i < 4; i++) {
    int n = n0 + ty + i * 8, k = k0 + tx;
    if (n < Npad && k < K) wt[(size_t)n * K + k] = __float2bfloat16(tile[tx][ty + i * 8]);
  }
}

// ---------------- bf16 MFMA GEMM: C[M,N] = A[M,K] @ Bt[N,K]^T ---------------
// m97 structure: BK=32, global_load_lds(16B), linear LDS, 2 barriers/K-step.
template<int BM, int BN, int WN, int MR, int NR>
__global__ __launch_bounds__(256) void mfma_gemm_kernel(
    const bf16* __restrict__ A, const bf16* __restrict__ Bt,
    const float* __restrict__ bias, int nbias,
    const float* __restrict__ resid,
    float* __restrict__ C, int ldc, int K) {
  constexpr int ROWS = BM + BN;            // LDS rows, 64 B each
  constexpr int ISS  = ROWS / 64;          // global_load_lds issues per wave
  __shared__ __align__(16) bf16 sAB[ROWS][32];  // A rows then B(t) rows

  int wid = threadIdx.x >> 6, lane = threadIdx.x & 63;
  int row0 = blockIdx.y * BM, col0 = blockIdx.x * BN;
  int wr = (wid / WN) * (MR * 16);
  int wc = (wid % WN) * (NR * 16);

  f32x4 acc[MR][NR];
#pragma unroll
  for (int m = 0; m < MR; m++)
#pragma unroll
    for (int n = 0; n < NR; n++) acc[m][n] = (f32x4){0.f, 0.f, 0.f, 0.f};

  int lr = lane >> 2;            // row within 16-row issue group
  int lc = (lane & 3) * 8;       // bf16 offset within 64B row

  for (int k0 = 0; k0 < K; k0 += 32) {
#pragma unroll
    for (int i = 0; i < ISS; i++) {
      int rb = (wid * ISS + i) * 16;
      int r = rb + lr;
      const bf16* src = (r < BM)
          ? A  + (size_t)(row0 + r) * K + k0 + lc
          : Bt + (size_t)(col0 + (r - BM)) * K + k0 + lc;
      __builtin_amdgcn_global_load_lds(
          (const __attribute__((address_space(1))) void*)src,
          (__attribute__((address_space(3))) void*)&sAB[rb][0], 16, 0, 0);
    }
    asm volatile("s_waitcnt vmcnt(0)" ::: "memory");
    __syncthreads();

    short8 a[MR], b[NR];
    int kk = (lane >> 4) * 8;
#pragma unroll
    for (int m = 0; m < MR; m++)
      a[m] = *(const short8*)&sAB[wr + m * 16 + (lane & 15)][kk];
#pragma unroll
    for (int n = 0; n < NR; n++)
      b[n] = *(const short8*)&sAB[BM + wc + n * 16 + (lane & 15)][kk];
#pragma unroll
    for (int m = 0; m < MR; m++)
#pragma unroll
      for (int n = 0; n < NR; n++)
        acc[m][n] = __builtin_amdgcn_mfma_f32_16x16x32_bf16(a[m], b[n], acc[m][n], 0, 0, 0);
    __syncthreads();
  }

  int crow = row0 + wr + (lane >> 4) * 4;
  int ccol = col0 + wc + (lane & 15);
#pragma unroll
  for (int m = 0; m < MR; m++) {
#pragma unroll
    for (int n = 0; n < NR; n++) {
      int colg = ccol + n * 16;
      float bv = bias ? ((colg < nbias) ? bias[colg] : 0.f) : 0.f;
#pragma unroll
      for (int j = 0; j < 4; j++) {
        int rowg = crow + m * 16 + j;
        float v = acc[m][n][j] + bv;
        if (resid) v += resid[(size_t)rowg * ldc + colg];
        C[(size_t)rowg * ldc + colg] = v;
      }
    }
  }
}

// ---------------- tree scan: register state + intra-wave parent gather ------
// thread = pl*16 + w  (w in LOW 4 lane bits -> gather along w is intra-wave).
// State h[16] in VGPRs; B/C/x/dt/dA/parent staged per 8-step chunk in LDS.
__global__ __launch_bounds__(256) void tree_scan_kernel(
    const float* __restrict__ proj, const int* __restrict__ parent,
    const float* __restrict__ A_log, const float* __restrict__ dt_bias,
    const float* __restrict__ Dp, float* __restrict__ y) {
  const int tid = threadIdx.x;
  const int ps = blockIdx.x & 3;
  const int h  = (blockIdx.x >> 2) & 15;
  const int b  = blockIdx.x >> 6;
  const int pl = tid >> 4;        // p within 16-chunk
  const int w  = tid & 15;        // tree width position
  const int lane = tid & 63;

  __shared__ float Bs[8][16][17];
  __shared__ float Cs[8][16][17];
  __shared__ float Xs[8][16][17];
  __shared__ float dts[8][16];
  __shared__ float dAs[8][16];
  __shared__ int   pars[8][16];

  const float Ah  = -expf(A_log[h]);
  const float dtb = dt_bias[h];
  const float Dh  = Dp[h];
  const int xcol = 1024 + (h << 6) + (ps << 4);
  const int src = ((lane & 48) << 2);  // pl-group base, byte addressed

  float hst[16];
#pragma unroll
  for (int n = 0; n < 16; n++) hst[n] = 0.f;

  for (int c = 0; c < 8; c++) {
    const int t0 = c * 8;
    __syncthreads();  // previous chunk's compute done
#pragma unroll
    for (int k = 0; k < 8; k++) {
      int j = tid + (k << 8);               // 0..2047
      int tt = j >> 8, wv = (j >> 4) & 15, n = j & 15;
      size_t row = ((size_t)(b * NT + t0 + tt)) * NW + wv;
      const float* pb = proj + row * PROJ_LD;
      Bs[tt][wv][n] = pb[2048 + n];
      Cs[tt][wv][n] = pb[2064 + n];
      Xs[tt][wv][n] = pb[xcol + n];
    }
    if (tid < 128) {
      int tt = tid >> 4, wv = tid & 15;
      size_t row = ((size_t)(b * NT + t0 + tt)) * NW + wv;
      float dtr = proj[row * PROJ_LD + 2080 + h] + dtb;
      float dtv = (dtr > 20.f) ? dtr : log1pf(expf(dtr));
      dts[tt][wv] = dtv;
      dAs[tt][wv] = expf(dtv * Ah);
      pars[tt][wv] = parent[row];
    }
    __syncthreads();  // staging visible

    for (int tt = 0; tt < 8; tt++) {
      int   par = pars[tt][w];
      float dA  = dAs[tt][w];
      float dt  = dts[tt][w];
      float xv  = Xs[tt][w][pl];
      float dtx = dt * xv;
      int gidx = src | (par << 2);
      float yv = 0.f;
#pragma unroll
      for (int n = 0; n < 16; n++) {
        int hpi = __builtin_amdgcn_ds_bpermute(gidx, __float_as_int(hst[n]));
        float hn = fmaf(dA, __int_as_float(hpi), dtx * Bs[tt][w][n]);
        hst[n] = hn;
        yv = fmaf(hn, Cs[tt][w][n], yv);
      }
      size_t row = ((size_t)(b * NT + t0 + tt)) * NW + w;
      y[row * D_INNER + (h << 6) + (ps << 4) + pl] = fmaf(Dh, xv, yv);
    }
  }
}

// ---------------- gated RMSNorm -> bf16 -------------------------------------
__global__ __launch_bounds__(256) void gate_rms_kernel(
    const float* __restrict__ yin, const float* __restrict__ proj,
    const float* __restrict__ norm_w, bf16* __restrict__ out) {
  __shared__ float sbuf[8];
  int row = blockIdx.x;
  const float* yr = yin + (size_t)row * D_INNER;
  const float* zr = proj + (size_t)row * PROJ_LD;  // z = cols [0,1024)
  int c = threadIdx.x * 4;
  float4 y4 = *(const float4*)&yr[c];
  float4 z4 = *(const float4*)&zr[c];
  const float* yp = (const float*)&y4;
  const float* zp = (const float*)&z4;
  float gv[4];
  float ss = 0.f;
#pragma unroll
  for (int j = 0; j < 4; j++) {
    float z = zp[j];
    float t = yp[j] * (z / (1.f + expf(-z)));
    gv[j] = t;
    ss += t * t;
  }
  ss = block_sum(ss, sbuf);
  float scale = rsqrtf(ss * (1.f / 1024.f) + 1e-5f);
  bf16 o4[4];
#pragma unroll
  for (int j = 0; j < 4; j++) o4[j] = __float2bfloat16(gv[j] * scale * norm_w[c + j]);
  *(uint2*)&out[(size_t)row * D_INNER + c] = *(uint2*)o4;
}

// ---------------- FF gate -> bf16 -------------------------------------------
__global__ __launch_bounds__(256) void ffgate_kernel(
    const float* __restrict__ f, bf16* __restrict__ out) {
  size_t i4 = (size_t)blockIdx.x * blockDim.x + threadIdx.x;
  int row = (int)(i4 >> 8);
  int c = ((int)i4 & 255) * 4;
  const float* fr = f + (size_t)row * 2048;
  float4 a = *(const float4*)&fr[c];
  float4 g = *(const float4*)&fr[1024 + c];
  const float* ap = (const float*)&a;
  const float* gp = (const float*)&g;
  bf16 o4[4];
#pragma unroll
  for (int j = 0; j < 4; j++) {
    float z = gp[j];
    o4[j] = __float2bfloat16(ap[j] * (z / (1.f + expf(-z))));
  }
  *(uint2*)&out[(size_t)row * 1024 + c] = *(uint2*)o4;
}

extern "C" void kernel_launch(void* const* d_in, const int* in_sizes, int n_in,
                              void* d_out, int out_size, void* d_ws, size_t ws_size,
                              hipStream_t stream) {
  const float* x       = (const float*)d_in[0];
  const int*   parent  = (const int*)d_in[1];
  const float* ln1_w   = (const float*)d_in[2];
  const float* ln1_b   = (const float*)d_in[3];
  const float* in_w    = (const float*)d_in[4];
  const float* in_b    = (const float*)d_in[5];
  const float* A_log   = (const float*)d_in[6];
  const float* dt_bias = (const float*)d_in[7];
  const float* Dp      = (const float*)d_in[8];
  const float* norm_w  = (const float*)d_in[9];
  const float* out_w   = (const float*)d_in[10];
  const float* out_b   = (const float*)d_in[11];
  const float* ln2_w   = (const float*)d_in[12];
  const float* ln2_b   = (const float*)d_in[13];
  const float* ff1_w   = (const float*)d_in[14];
  const float* ff1_b   = (const float*)d_in[15];
  const float* ff2_w   = (const float*)d_in[16];
  const float* ff2_b   = (const float*)d_in[17];
  float* outp = (float*)d_out;

  char* wp = (char*)d_ws;
  bf16* xnb    = (bf16*)wp;  wp += (size_t)MROWS * D_MODEL * 2;
  bf16* in_wt  = (bf16*)wp;  wp += (size_t)PROJ_LD * D_MODEL * 2;
  bf16* out_wt = (bf16*)wp;  wp += (size_t)D_MODEL * D_INNER * 2;
  bf16* ff1_wt = (bf16*)wp;  wp += (size_t)2048 * D_MODEL * 2;
  bf16* ff2_wt = (bf16*)wp;  wp += (size_t)D_MODEL * D_INNER * 2;
  float* proj  = (float*)wp; wp += (size_t)MROWS * PROJ_LD * 4;  // reused for f
  float* yb    = (float*)wp; wp += (size_t)MROWS * D_INNER * 4;
  bf16* ygb    = (bf16*)wp;  wp += (size_t)MROWS * D_INNER * 2;
  float* xmid  = outp;  // d_out doubles as xmid

  dim3 blk(256);
  // weight converts (transpose to [N][K] bf16)
  wconv_t_kernel<<<dim3(PROJ_LD / 32, D_MODEL / 32), blk, 0, stream>>>(
      in_w, in_wt, D_MODEL, NPROJ, PROJ_LD);
  wconv_t_kernel<<<dim3(D_MODEL / 32, D_INNER / 32), blk, 0, stream>>>(
      out_w, out_wt, D_INNER, D_MODEL, D_MODEL);
  wconv_t_kernel<<<dim3(2048 / 32, D_MODEL / 32), blk, 0, stream>>>(
      ff1_w, ff1_wt, D_MODEL, 2048, 2048);
  wconv_t_kernel<<<dim3(D_MODEL / 32, D_INNER / 32), blk, 0, stream>>>(
      ff2_w, ff2_wt, D_INNER, D_MODEL, D_MODEL);

  // 1) LN1 -> bf16
  ln512_bf16_kernel<<<MROWS, blk, 0, stream>>>(x, ln1_w, ln1_b, xnb);
  // 2) in-proj GEMM -> proj (fp32, padded ld)
  mfma_gemm_kernel<128, 128, 2, 4, 4><<<dim3(PROJ_LD / 128, MROWS / 128), blk, 0, stream>>>(
      xnb, in_wt, in_b, NPROJ, nullptr, proj, PROJ_LD, D_MODEL);
  // 3) tree scan -> yb
  tree_scan_kernel<<<NB * NHEAD * 4, blk, 0, stream>>>(proj, parent, A_log,
                                                       dt_bias, Dp, yb);
  // 4) gated RMSNorm -> ygb (bf16)
  gate_rms_kernel<<<MROWS, blk, 0, stream>>>(yb, proj, norm_w, ygb);
  // 5) out-proj GEMM + resid(x) -> xmid
  mfma_gemm_kernel<64, 128, 4, 4, 2><<<dim3(D_MODEL / 128, MROWS / 64), blk, 0, stream>>>(
      ygb, out_wt, out_b, D_MODEL, x, xmid, D_MODEL, D_INNER);
  // 6) LN2 -> xnb (reuse)
  ln512_bf16_kernel<<<MROWS, blk, 0, stream>>>(xmid, ln2_w, ln2_b, xnb);
  // 7) FF1 GEMM -> f (reuse proj buffer, ld 2048)
  mfma_gemm_kernel<128, 128, 2, 4, 4><<<dim3(2048 / 128, MROWS / 128), blk, 0, stream>>>(
      xnb, ff1_wt, ff1_b, 2048, nullptr, proj, 2048, D_MODEL);
  // 8) FF gate -> ygb (reuse)
  ffgate_kernel<<<MROWS, blk, 0, stream>>>(proj, ygb);
  // 9) FF2 GEMM + resid(xmid) -> d_out
  mfma_gemm_kernel<64, 128, 4, 4, 2><<<dim3(D_MODEL / 128, MROWS / 64), blk, 0, stream>>>(
      ygb, ff2_wt, ff2_b, D_MODEL, xmid, outp, D_MODEL, D_INNER);
}